// Round 1
// baseline (2368.738 us; speedup 1.0000x reference)
//
#include <hip/hip_runtime.h>
#include <cstdint>

static constexpr int Ln = 1024;   // nodes
static constexpr int Cn = 16;     // in channels
static constexpr int On = 64;     // out channels
static constexpr int W1K = 15 * Cn; // 240

// ---- workspace layout (float offsets) ----
static constexpr size_t WS_COL  = 0;                        // [L][C]  col_sum[i,c] = sum_j Tm[i,j,c]
static constexpr size_t WS_ROW  = WS_COL  + (size_t)Ln*Cn;  // [L][C]  row_sum[j,c] = sum_i Tm[i,j,c]
static constexpr size_t WS_DIAG = WS_ROW  + (size_t)Ln*Cn;  // [L][C]
static constexpr size_t WS_TR   = WS_DIAG + (size_t)Ln*Cn;  // [C]
static constexpr size_t WS_ALL  = WS_TR   + Cn;             // [C]
static constexpr size_t WS_C0   = WS_ALL  + Cn;             // [O]
static constexpr size_t WS_A    = WS_C0   + On;             // [L][O] terms depending on j (c0 folded in)
static constexpr size_t WS_B    = WS_A    + (size_t)Ln*On;  // [L][O] terms depending on i
static constexpr size_t WS_D    = WS_B    + (size_t)Ln*On;  // [L][O] diagonal-only terms
static constexpr size_t WS_W7T  = WS_D    + (size_t)Ln*On;  // [C][O] W1 block 6 (transpose term)
static constexpr size_t WS_W8T  = WS_W7T  + (size_t)Cn*On;  // [C][O] W1 block 7 (identity term)
static constexpr size_t WS_RPART= WS_W8T  + (size_t)Cn*On;  // [16][L][C] row_sum partials

__device__ __forceinline__ float4 masked4(const float* __restrict__ tp,
                                          const int* __restrict__ mp) {
  float4 t = *(const float4*)tp;
  int4  m = *(const int4*)mp;
  float4 r;
  r.x = m.x ? t.x : 0.f;
  r.y = m.y ? t.y : 0.f;
  r.z = m.z ? t.z : 0.f;
  r.w = m.w ? t.w : 0.f;
  return r;
}

// Swizzled LDS index for the 16x16xC tile planes.
// Logical element b (0..255) of channel ch lives at  ch*256 + (swz(b) ^ f(ch)).
// swz: XOR low nibble with high nibble (makes both row-major and col-major
// 16-strided reads <=2-way). f(ch): spreads the 4-channel-group store across
// bank bits 2 and 4 so the staging stores are 2-way instead of 4-way.
__device__ __forceinline__ int sidx(int ch, int b) {
  const int s = (b & 0xF0) | ((b ^ (b >> 4)) & 15);
  const int f = (((ch >> 2) & 1) << 4) | (((ch >> 3) & 1) << 2);
  return ch * 256 + (s ^ f);
}

// col_sum[i,c] = sum_j Tm[i,j,c]; also extracts diag. One block per row i. Coalesced.
__global__ __launch_bounds__(256) void k_colsum_diag(const float* __restrict__ T,
                                                     const int* __restrict__ Mk,
                                                     float* __restrict__ ws) {
  const int i = blockIdx.x;
  const int t = threadIdx.x;
  const float* rowT = T  + (size_t)i * Ln * Cn;
  const int*   rowM = Mk + (size_t)i * Ln * Cn;
  float s[Cn];
#pragma unroll
  for (int c = 0; c < Cn; c++) s[c] = 0.f;
  for (int j = t; j < Ln; j += 256) {
#pragma unroll
    for (int q = 0; q < 4; q++) {
      float4 v = masked4(rowT + j * Cn + q * 4, rowM + j * Cn + q * 4);
      s[q*4+0] += v.x; s[q*4+1] += v.y; s[q*4+2] += v.z; s[q*4+3] += v.w;
      if (j == i) {
        float* dg = ws + WS_DIAG + (size_t)i * Cn + q * 4;
        dg[0] = v.x; dg[1] = v.y; dg[2] = v.z; dg[3] = v.w;
      }
    }
  }
  __shared__ float red[256][Cn + 1];
#pragma unroll
  for (int c = 0; c < Cn; c++) red[t][c] = s[c];
  __syncthreads();
  for (int off = 128; off > 0; off >>= 1) {
    if (t < off) {
#pragma unroll
      for (int c = 0; c < Cn; c++) red[t][c] += red[t + off][c];
    }
    __syncthreads();
  }
  if (t < Cn) ws[WS_COL + (size_t)i * Cn + t] = red[0][t];
}

// Coalesced row_sum partials: block (bj, bi) handles 64 cols x 64-row band.
__global__ __launch_bounds__(256) void k_rowsum_part(const float* __restrict__ T,
                                                     const int* __restrict__ Mk,
                                                     float* __restrict__ ws) {
  const int bj = blockIdx.x, bi = blockIdx.y, t = threadIdx.x;
  const int jl = t >> 2, c4 = t & 3;
  const int j = bj * 64 + jl;
  float4 acc = {0.f, 0.f, 0.f, 0.f};
  for (int ii = 0; ii < 64; ii++) {
    const int i = bi * 64 + ii;
    const size_t base = ((size_t)i * Ln + j) * Cn + c4 * 4;
    float4 v = masked4(T + base, Mk + base);
    acc.x += v.x; acc.y += v.y; acc.z += v.z; acc.w += v.w;
  }
  *(float4*)(ws + WS_RPART + ((size_t)bi * Ln + j) * Cn + c4 * 4) = acc;
}

__global__ __launch_bounds__(256) void k_rowsum_reduce(float* __restrict__ ws) {
  const int idx = blockIdx.x * 256 + threadIdx.x;  // 16384 = 1024*16
  const int j = idx >> 4, c = idx & 15;
  float s = 0.f;
#pragma unroll
  for (int p = 0; p < 16; p++)
    s += ws[WS_RPART + ((size_t)p * Ln + j) * Cn + c];
  ws[WS_ROW + (size_t)j * Cn + c] = s;
}

// trace, all_sum, c0, transposed W7/W8 blocks. Single block.
__global__ __launch_bounds__(256) void k_scalars(const float* __restrict__ W1,
                                                 const float* __restrict__ b1,
                                                 float* __restrict__ ws) {
  const int t = threadIdx.x;
  __shared__ float redt[16][17], reda[16][17];
  __shared__ float trs[Cn], als[Cn];

  for (int idx = t; idx < 2 * Cn * On; idx += 256) {
    int which = idx >> 10;      // Cn*On == 1024
    int rem = idx & 1023;
    int c = rem >> 6, o = rem & 63;
    ws[(which ? WS_W8T : WS_W7T) + rem] = W1[o * W1K + (which ? 7 : 6) * Cn + c];
  }
  {
    int c = t & 15, seg = t >> 4;
    float a = 0.f, b = 0.f;
    for (int i = seg * 64; i < seg * 64 + 64; i++) {
      a += ws[WS_DIAG + (size_t)i * Cn + c];
      b += ws[WS_COL  + (size_t)i * Cn + c];
    }
    redt[seg][c] = a;
    reda[seg][c] = b;
  }
  __syncthreads();
  if (t < Cn) {
    float ta = 0.f, tb = 0.f;
    for (int s = 0; s < 16; s++) { ta += redt[s][t]; tb += reda[s][t]; }
    ws[WS_TR + t] = ta; ws[WS_ALL + t] = tb;
    trs[t] = ta; als[t] = tb;
  }
  __syncthreads();
  if (t < On) {
    float acc = b1[t];
#pragma unroll
    for (int c = 0; c < Cn; c++)
      acc += W1[t * W1K + 8 * Cn + c] * trs[c] + W1[t * W1K + 14 * Cn + c] * als[c];
    ws[WS_C0 + t] = acc;
  }
}

// Per-node A/B/D vectors. One block per node, thread = output channel.
// c0 (bias + trace/all_sum terms) is folded into A so k_main adds it once.
__global__ __launch_bounds__(64) void k_node_terms(const float* __restrict__ W1,
                                                   float* __restrict__ ws) {
  const int n = blockIdx.x;
  const int o = threadIdx.x;
  __shared__ float sd[Cn], sr[Cn], sc[Cn], st[Cn], sa[Cn];
  if (o < Cn) {
    sd[o] = ws[WS_DIAG + (size_t)n * Cn + o];
    sr[o] = ws[WS_ROW  + (size_t)n * Cn + o];
    sc[o] = ws[WS_COL  + (size_t)n * Cn + o];
    st[o] = ws[WS_TR + o];
    sa[o] = ws[WS_ALL + o];
  }
  __syncthreads();
  const float* w = W1 + o * W1K;
  float a = 0.f, b = 0.f, d = 0.f;
#pragma unroll
  for (int c = 0; c < Cn; c++) {
    a += w[ 1*Cn + c] * sd[c] + w[ 9*Cn + c] * sr[c] + w[10*Cn + c] * sc[c];
    b += w[ 2*Cn + c] * sd[c] + w[12*Cn + c] * sc[c] + w[13*Cn + c] * sr[c];
    d += w[ 0*Cn + c] * sd[c] + w[ 3*Cn + c] * sr[c] + w[ 4*Cn + c] * sc[c]
       + w[ 5*Cn + c] * st[c] + w[11*Cn + c] * sa[c];
  }
  ws[WS_A + (size_t)n * On + o] = a + ws[WS_C0 + o];   // fold c0 here
  ws[WS_B + (size_t)n * On + o] = b;
  ws[WS_D + (size_t)n * On + o] = d;
}

// Main fused kernel: triangular pair-tile grid (2080 blocks), 512 threads.
// Half 0 computes out[I-tile, J-tile], half 1 computes out[J-tile, I-tile].
// All per-pair state in fully-unrolled float4 register chunks (no scratch).
static constexpr int NODE_S = 68;  // padded stride for node-vector LDS (float4 reads 2-way)

__global__ __launch_bounds__(512, 2) void k_main(const float* __restrict__ T,
                                                 const int* __restrict__ Mk,
                                                 const float* __restrict__ W2,
                                                 const float* __restrict__ b2,
                                                 const float* __restrict__ ws,
                                                 float* __restrict__ out) {
  // ---- decode triangular block index: base(I) = (129I - I^2)/2 ----
  const int kb = blockIdx.x;
  int I = (int)((129.0f - sqrtf(16641.0f - 8.0f * (float)kb)) * 0.5f);
  while ((I + 1) * 129 - (I + 1) * (I + 1) <= 2 * kb) ++I;
  while (I * 129 - I * I > 2 * kb) --I;
  const int J = I + (kb - (I * 129 - I * I) / 2);

  const int t = threadIdx.x;
  const int half = t >> 8, tl = t & 255;

  __shared__ float sA[16 * 256];   // swizzled: element b of channel c at sidx(c,b); b = ra*16+ca -> Tm[I*16+ra, J*16+ca, c]
  __shared__ float sB[16 * 256];   // b = ca*16+rb -> Tm[J*16+rb, I*16+ca, c]
  __shared__ float nAJ[16 * NODE_S], nBI[16 * NODE_S], nAI[16 * NODE_S], nBJ[16 * NODE_S];

  // ---- stage T tiles (mask applied here) ----
#pragma unroll
  for (int kk = 0; kk < 2; kk++) {
    const int fq = t + kk * 512;           // float4 id 0..1023
    const int r = fq >> 6, rem = fq & 63, col = rem >> 2, c4 = rem & 3;
    const int bA = r * 16 + col;
    const int bB = col * 16 + r;           // transposed store
    {
      const size_t g = (((size_t)(I * 16 + r)) * Ln + (J * 16 + col)) * Cn + c4 * 4;
      float4 v = masked4(T + g, Mk + g);
      sA[sidx(c4 * 4 + 0, bA)] = v.x;
      sA[sidx(c4 * 4 + 1, bA)] = v.y;
      sA[sidx(c4 * 4 + 2, bA)] = v.z;
      sA[sidx(c4 * 4 + 3, bA)] = v.w;
    }
    {
      const size_t g = (((size_t)(J * 16 + r)) * Ln + (I * 16 + col)) * Cn + c4 * 4;
      float4 v = masked4(T + g, Mk + g);
      sB[sidx(c4 * 4 + 0, bB)] = v.x;
      sB[sidx(c4 * 4 + 1, bB)] = v.y;
      sB[sidx(c4 * 4 + 2, bB)] = v.z;
      sB[sidx(c4 * 4 + 3, bB)] = v.w;
    }
  }
  // ---- stage node vectors (A/B for both tiles), stride NODE_S ----
#pragma unroll
  for (int kk = 0; kk < 8; kk++) {
    const int f = t + kk * 512;            // 0..4095
    const int arr = f >> 10, rem = f & 1023, nl = rem >> 6, o = rem & 63;
    switch (arr) {
      case 0: nAJ[nl * NODE_S + o] = ws[WS_A + ((size_t)(J * 16 + nl)) * On + o]; break;
      case 1: nBI[nl * NODE_S + o] = ws[WS_B + ((size_t)(I * 16 + nl)) * On + o]; break;
      case 2: nAI[nl * NODE_S + o] = ws[WS_A + ((size_t)(I * 16 + nl)) * On + o]; break;
      default: nBJ[nl * NODE_S + o] = ws[WS_B + ((size_t)(J * 16 + nl)) * On + o]; break;
    }
  }
  __syncthreads();

  const int r = tl >> 4, col = tl & 15;
  const int i = (half ? J : I) * 16 + r;
  const int j = (half ? I : J) * 16 + col;
  const int braw = half ? (col * 16 + r) : tl;
  const float* Pij = half ? sB : sA;       // Tm[i,j,:]  (identity term, W8)
  const float* Pji = half ? sA : sB;       // Tm[j,i,:]  (transpose term, W7)
  const float* pA = (half ? nAI : nAJ) + col * NODE_S;
  const float* pB = (half ? nBJ : nBI) + r * NODE_S;

  // ---- hoist tile channels into registers (conflict-free swizzled reads) ----
  float a[Cn], b[Cn];
#pragma unroll
  for (int c = 0; c < Cn; c++) {
    const int ix = sidx(c, braw);
    a[c] = Pji[ix];
    b[c] = Pij[ix];
  }

  // ---- v = A[j] + B[i] (+ D[i] on diagonal); c0 already folded into A ----
  float4 v4[16];
#pragma unroll
  for (int o4 = 0; o4 < 16; o4++) {
    float4 x = *(const float4*)(pA + o4 * 4);
    const float4 y = *(const float4*)(pB + o4 * 4);
    x.x += y.x; x.y += y.y; x.z += y.z; x.w += y.w;
    v4[o4] = x;
  }
  if (i == j) {
    const float* Di = ws + WS_D + (size_t)i * On;
#pragma unroll
    for (int o4 = 0; o4 < 16; o4++) {
      v4[o4].x += Di[o4 * 4 + 0];
      v4[o4].y += Di[o4 * 4 + 1];
      v4[o4].z += Di[o4 * 4 + 2];
      v4[o4].w += Di[o4 * 4 + 3];
    }
  }

  // ---- v += W7^T * Tm[j,i] + W8^T * Tm[i,j];  relu ----
  const float* W7t = ws + WS_W7T;
  const float* W8t = ws + WS_W8T;
#pragma unroll
  for (int o4 = 0; o4 < 16; o4++) {
    float4 acc = v4[o4];
#pragma unroll
    for (int c = 0; c < Cn; c++) {
      const float ac = a[c], bc = b[c];
      const float* w7 = W7t + c * On + o4 * 4;
      const float* w8 = W8t + c * On + o4 * 4;
      acc.x += w7[0] * ac + w8[0] * bc;
      acc.y += w7[1] * ac + w8[1] * bc;
      acc.z += w7[2] * ac + w8[2] * bc;
      acc.w += w7[3] * ac + w8[3] * bc;
    }
    acc.x = fmaxf(acc.x, 0.f);
    acc.y = fmaxf(acc.y, 0.f);
    acc.z = fmaxf(acc.z, 0.f);
    acc.w = fmaxf(acc.w, 0.f);
    v4[o4] = acc;
  }

  // ---- out = W2 * h + b2 (64x64 GEMV, fully unrolled, W2 via scalar loads) ----
  float4 acc[16];
#pragma unroll
  for (int p4 = 0; p4 < 16; p4++) {
    acc[p4].x = b2[p4 * 4 + 0];
    acc[p4].y = b2[p4 * 4 + 1];
    acc[p4].z = b2[p4 * 4 + 2];
    acc[p4].w = b2[p4 * 4 + 3];
  }
#pragma unroll
  for (int o4 = 0; o4 < 16; o4++) {
    const float4 h = v4[o4];
#pragma unroll
    for (int p4 = 0; p4 < 16; p4++) {
      const float* w0 = W2 + (size_t)(p4 * 4 + 0) * On + o4 * 4;
      const float* w1 = W2 + (size_t)(p4 * 4 + 1) * On + o4 * 4;
      const float* w2 = W2 + (size_t)(p4 * 4 + 2) * On + o4 * 4;
      const float* w3 = W2 + (size_t)(p4 * 4 + 3) * On + o4 * 4;
      acc[p4].x += w0[0] * h.x + w0[1] * h.y + w0[2] * h.z + w0[3] * h.w;
      acc[p4].y += w1[0] * h.x + w1[1] * h.y + w1[2] * h.z + w1[3] * h.w;
      acc[p4].z += w2[0] * h.x + w2[1] * h.y + w2[2] * h.z + w2[3] * h.w;
      acc[p4].w += w3[0] * h.x + w3[1] * h.y + w3[2] * h.z + w3[3] * h.w;
    }
  }

  float* op = out + ((size_t)i * Ln + j) * On;
#pragma unroll
  for (int p4 = 0; p4 < 16; p4++)
    *(float4*)(op + p4 * 4) = acc[p4];
}

extern "C" void kernel_launch(void* const* d_in, const int* in_sizes, int n_in,
                              void* d_out, int out_size, void* d_ws, size_t ws_size,
                              hipStream_t stream) {
  (void)in_sizes; (void)n_in; (void)out_size; (void)ws_size;
  const float* T  = (const float*)d_in[0];
  const int*   Mk = (const int*)d_in[1];
  const float* W1 = (const float*)d_in[2];
  const float* b1 = (const float*)d_in[3];
  const float* W2 = (const float*)d_in[4];
  const float* b2 = (const float*)d_in[5];
  float* out = (float*)d_out;
  float* ws  = (float*)d_ws;

  k_colsum_diag<<<Ln, 256, 0, stream>>>(T, Mk, ws);
  {
    dim3 g(16, 16);
    k_rowsum_part<<<g, 256, 0, stream>>>(T, Mk, ws);
  }
  k_rowsum_reduce<<<64, 256, 0, stream>>>(ws);
  k_scalars<<<1, 256, 0, stream>>>(W1, b1, ws);
  k_node_terms<<<Ln, 64, 0, stream>>>(W1, ws);
  {
    const int nb = (Ln / 16) * (Ln / 16 + 1) / 2;  // 2080 triangular tile pairs
    k_main<<<nb, 512, 0, stream>>>(T, Mk, W2, b2, ws, out);
  }
}

// Round 2
// 903.160 us; speedup vs baseline: 2.6227x; 2.6227x over previous
//
#include <hip/hip_runtime.h>
#include <cstdint>

static constexpr int Ln = 1024;   // nodes
static constexpr int Cn = 16;     // in channels
static constexpr int On = 64;     // out channels
static constexpr int W1K = 15 * Cn; // 240

// ---- workspace layout (float offsets) ----
static constexpr size_t WS_COL  = 0;                        // [L][C]  col_sum[i,c] = sum_j Tm[i,j,c]
static constexpr size_t WS_ROW  = WS_COL  + (size_t)Ln*Cn;  // [L][C]  row_sum[j,c] = sum_i Tm[i,j,c]
static constexpr size_t WS_DIAG = WS_ROW  + (size_t)Ln*Cn;  // [L][C]
static constexpr size_t WS_TR   = WS_DIAG + (size_t)Ln*Cn;  // [C]
static constexpr size_t WS_ALL  = WS_TR   + Cn;             // [C]
static constexpr size_t WS_C0   = WS_ALL  + Cn;             // [O]
static constexpr size_t WS_A    = WS_C0   + On;             // [L][O] terms depending on j (c0 folded in)
static constexpr size_t WS_B    = WS_A    + (size_t)Ln*On;  // [L][O] terms depending on i
static constexpr size_t WS_D    = WS_B    + (size_t)Ln*On;  // [L][O] diagonal-only terms
static constexpr size_t WS_W7T  = WS_D    + (size_t)Ln*On;  // [C][O] W1 block 6 (transpose term)
static constexpr size_t WS_W8T  = WS_W7T  + (size_t)Cn*On;  // [C][O] W1 block 7 (identity term)
static constexpr size_t WS_RPART= WS_W8T  + (size_t)Cn*On;  // [16][L][C] row_sum partials

__device__ __forceinline__ float4 masked4(const float* __restrict__ tp,
                                          const int* __restrict__ mp) {
  float4 t = *(const float4*)tp;
  int4  m = *(const int4*)mp;
  float4 r;
  r.x = m.x ? t.x : 0.f;
  r.y = m.y ? t.y : 0.f;
  r.z = m.z ? t.z : 0.f;
  r.w = m.w ? t.w : 0.f;
  return r;
}

// Swizzled LDS index for the 16x16xC tile planes. Verified round 1:
// bank conflicts 8.5M -> 0.53M. Keep.
__device__ __forceinline__ int sidx(int ch, int b) {
  const int s = (b & 0xF0) | ((b ^ (b >> 4)) & 15);
  const int f = (((ch >> 2) & 1) << 4) | (((ch >> 3) & 1) << 2);
  return ch * 256 + (s ^ f);
}

// col_sum[i,c] = sum_j Tm[i,j,c]; also extracts diag. One block per row i. Coalesced.
__global__ __launch_bounds__(256) void k_colsum_diag(const float* __restrict__ T,
                                                     const int* __restrict__ Mk,
                                                     float* __restrict__ ws) {
  const int i = blockIdx.x;
  const int t = threadIdx.x;
  const float* rowT = T  + (size_t)i * Ln * Cn;
  const int*   rowM = Mk + (size_t)i * Ln * Cn;
  float s[Cn];
#pragma unroll
  for (int c = 0; c < Cn; c++) s[c] = 0.f;
  for (int j = t; j < Ln; j += 256) {
#pragma unroll
    for (int q = 0; q < 4; q++) {
      float4 v = masked4(rowT + j * Cn + q * 4, rowM + j * Cn + q * 4);
      s[q*4+0] += v.x; s[q*4+1] += v.y; s[q*4+2] += v.z; s[q*4+3] += v.w;
      if (j == i) {
        float* dg = ws + WS_DIAG + (size_t)i * Cn + q * 4;
        dg[0] = v.x; dg[1] = v.y; dg[2] = v.z; dg[3] = v.w;
      }
    }
  }
  __shared__ float red[256][Cn + 1];
#pragma unroll
  for (int c = 0; c < Cn; c++) red[t][c] = s[c];
  __syncthreads();
  for (int off = 128; off > 0; off >>= 1) {
    if (t < off) {
#pragma unroll
      for (int c = 0; c < Cn; c++) red[t][c] += red[t + off][c];
    }
    __syncthreads();
  }
  if (t < Cn) ws[WS_COL + (size_t)i * Cn + t] = red[0][t];
}

// Coalesced row_sum partials: block (bj, bi) handles 64 cols x 64-row band.
__global__ __launch_bounds__(256) void k_rowsum_part(const float* __restrict__ T,
                                                     const int* __restrict__ Mk,
                                                     float* __restrict__ ws) {
  const int bj = blockIdx.x, bi = blockIdx.y, t = threadIdx.x;
  const int jl = t >> 2, c4 = t & 3;
  const int j = bj * 64 + jl;
  float4 acc = {0.f, 0.f, 0.f, 0.f};
  for (int ii = 0; ii < 64; ii++) {
    const int i = bi * 64 + ii;
    const size_t base = ((size_t)i * Ln + j) * Cn + c4 * 4;
    float4 v = masked4(T + base, Mk + base);
    acc.x += v.x; acc.y += v.y; acc.z += v.z; acc.w += v.w;
  }
  *(float4*)(ws + WS_RPART + ((size_t)bi * Ln + j) * Cn + c4 * 4) = acc;
}

__global__ __launch_bounds__(256) void k_rowsum_reduce(float* __restrict__ ws) {
  const int idx = blockIdx.x * 256 + threadIdx.x;  // 16384 = 1024*16
  const int j = idx >> 4, c = idx & 15;
  float s = 0.f;
#pragma unroll
  for (int p = 0; p < 16; p++)
    s += ws[WS_RPART + ((size_t)p * Ln + j) * Cn + c];
  ws[WS_ROW + (size_t)j * Cn + c] = s;
}

// trace, all_sum, c0, transposed W7/W8 blocks. Single block.
__global__ __launch_bounds__(256) void k_scalars(const float* __restrict__ W1,
                                                 const float* __restrict__ b1,
                                                 float* __restrict__ ws) {
  const int t = threadIdx.x;
  __shared__ float redt[16][17], reda[16][17];
  __shared__ float trs[Cn], als[Cn];

  for (int idx = t; idx < 2 * Cn * On; idx += 256) {
    int which = idx >> 10;      // Cn*On == 1024
    int rem = idx & 1023;
    int c = rem >> 6, o = rem & 63;
    ws[(which ? WS_W8T : WS_W7T) + rem] = W1[o * W1K + (which ? 7 : 6) * Cn + c];
  }
  {
    int c = t & 15, seg = t >> 4;
    float a = 0.f, b = 0.f;
    for (int i = seg * 64; i < seg * 64 + 64; i++) {
      a += ws[WS_DIAG + (size_t)i * Cn + c];
      b += ws[WS_COL  + (size_t)i * Cn + c];
    }
    redt[seg][c] = a;
    reda[seg][c] = b;
  }
  __syncthreads();
  if (t < Cn) {
    float ta = 0.f, tb = 0.f;
    for (int s = 0; s < 16; s++) { ta += redt[s][t]; tb += reda[s][t]; }
    ws[WS_TR + t] = ta; ws[WS_ALL + t] = tb;
    trs[t] = ta; als[t] = tb;
  }
  __syncthreads();
  if (t < On) {
    float acc = b1[t];
#pragma unroll
    for (int c = 0; c < Cn; c++)
      acc += W1[t * W1K + 8 * Cn + c] * trs[c] + W1[t * W1K + 14 * Cn + c] * als[c];
    ws[WS_C0 + t] = acc;
  }
}

// Per-node A/B/D vectors. One block per node, thread = output channel.
// c0 (bias + trace/all_sum terms) is folded into A so k_main adds it once.
__global__ __launch_bounds__(64) void k_node_terms(const float* __restrict__ W1,
                                                   float* __restrict__ ws) {
  const int n = blockIdx.x;
  const int o = threadIdx.x;
  __shared__ float sd[Cn], sr[Cn], sc[Cn], st[Cn], sa[Cn];
  if (o < Cn) {
    sd[o] = ws[WS_DIAG + (size_t)n * Cn + o];
    sr[o] = ws[WS_ROW  + (size_t)n * Cn + o];
    sc[o] = ws[WS_COL  + (size_t)n * Cn + o];
    st[o] = ws[WS_TR + o];
    sa[o] = ws[WS_ALL + o];
  }
  __syncthreads();
  const float* w = W1 + o * W1K;
  float a = 0.f, b = 0.f, d = 0.f;
#pragma unroll
  for (int c = 0; c < Cn; c++) {
    a += w[ 1*Cn + c] * sd[c] + w[ 9*Cn + c] * sr[c] + w[10*Cn + c] * sc[c];
    b += w[ 2*Cn + c] * sd[c] + w[12*Cn + c] * sc[c] + w[13*Cn + c] * sr[c];
    d += w[ 0*Cn + c] * sd[c] + w[ 3*Cn + c] * sr[c] + w[ 4*Cn + c] * sc[c]
       + w[ 5*Cn + c] * st[c] + w[11*Cn + c] * sa[c];
  }
  ws[WS_A + (size_t)n * On + o] = a + ws[WS_C0 + o];   // fold c0 here
  ws[WS_B + (size_t)n * On + o] = b;
  ws[WS_D + (size_t)n * On + o] = d;
}

// Main fused kernel: triangular pair-tile grid (2080 blocks), 512 threads.
// Register discipline: never two 64-float arrays live at once.
//   stage 1: c-outer (runtime loop), v4[16] (64 regs) accumulator.
//   stage 2: p4-outer (runtime loop), single float4 acc, direct global store.
// W7t/W8t/W2/b2 addresses are wave-uniform -> scalar (SMEM) loads, off VALU.
static constexpr int NODE_S = 68;  // padded stride for node-vector LDS

__global__ __launch_bounds__(512, 4) void k_main(const float* __restrict__ T,
                                                 const int* __restrict__ Mk,
                                                 const float* __restrict__ W2,
                                                 const float* __restrict__ b2,
                                                 const float* __restrict__ ws,
                                                 float* __restrict__ out) {
  // ---- decode triangular block index: base(I) = (129I - I^2)/2 ----
  const int kb = blockIdx.x;
  int I = (int)((129.0f - sqrtf(16641.0f - 8.0f * (float)kb)) * 0.5f);
  while ((I + 1) * 129 - (I + 1) * (I + 1) <= 2 * kb) ++I;
  while (I * 129 - I * I > 2 * kb) --I;
  const int J = I + (kb - (I * 129 - I * I) / 2);

  const int t = threadIdx.x;
  const int half = t >> 8, tl = t & 255;

  __shared__ float sA[16 * 256];   // swizzled; b = ra*16+ca -> Tm[I*16+ra, J*16+ca, c]
  __shared__ float sB[16 * 256];   // b = ca*16+rb -> Tm[J*16+rb, I*16+ca, c]
  __shared__ float nAJ[16 * NODE_S], nBI[16 * NODE_S], nAI[16 * NODE_S], nBJ[16 * NODE_S];

  // ---- stage T tiles (mask applied here) ----
#pragma unroll
  for (int kk = 0; kk < 2; kk++) {
    const int fq = t + kk * 512;           // float4 id 0..1023
    const int r = fq >> 6, rem = fq & 63, col = rem >> 2, c4 = rem & 3;
    const int bA = r * 16 + col;
    const int bB = col * 16 + r;           // transposed store
    {
      const size_t g = (((size_t)(I * 16 + r)) * Ln + (J * 16 + col)) * Cn + c4 * 4;
      float4 v = masked4(T + g, Mk + g);
      sA[sidx(c4 * 4 + 0, bA)] = v.x;
      sA[sidx(c4 * 4 + 1, bA)] = v.y;
      sA[sidx(c4 * 4 + 2, bA)] = v.z;
      sA[sidx(c4 * 4 + 3, bA)] = v.w;
    }
    {
      const size_t g = (((size_t)(J * 16 + r)) * Ln + (I * 16 + col)) * Cn + c4 * 4;
      float4 v = masked4(T + g, Mk + g);
      sB[sidx(c4 * 4 + 0, bB)] = v.x;
      sB[sidx(c4 * 4 + 1, bB)] = v.y;
      sB[sidx(c4 * 4 + 2, bB)] = v.z;
      sB[sidx(c4 * 4 + 3, bB)] = v.w;
    }
  }
  // ---- stage node vectors (A/B for both tiles), stride NODE_S ----
#pragma unroll
  for (int kk = 0; kk < 8; kk++) {
    const int f = t + kk * 512;            // 0..4095
    const int arr = f >> 10, rem = f & 1023, nl = rem >> 6, o = rem & 63;
    switch (arr) {
      case 0: nAJ[nl * NODE_S + o] = ws[WS_A + ((size_t)(J * 16 + nl)) * On + o]; break;
      case 1: nBI[nl * NODE_S + o] = ws[WS_B + ((size_t)(I * 16 + nl)) * On + o]; break;
      case 2: nAI[nl * NODE_S + o] = ws[WS_A + ((size_t)(I * 16 + nl)) * On + o]; break;
      default: nBJ[nl * NODE_S + o] = ws[WS_B + ((size_t)(J * 16 + nl)) * On + o]; break;
    }
  }
  __syncthreads();

  const int r = tl >> 4, col = tl & 15;
  const int i = (half ? J : I) * 16 + r;
  const int j = (half ? I : J) * 16 + col;
  const int braw = half ? (col * 16 + r) : tl;
  const float* Pij = half ? sB : sA;       // Tm[i,j,:]  (identity term, W8)
  const float* Pji = half ? sA : sB;       // Tm[j,i,:]  (transpose term, W7)
  const float* pA = (half ? nAI : nAJ) + col * NODE_S;
  const float* pB = (half ? nBJ : nBI) + r * NODE_S;

  // ---- v = A[j] + B[i] (+ D[i] on diagonal); c0 already folded into A ----
  float4 v4[16];
#pragma unroll
  for (int o4 = 0; o4 < 16; o4++) {
    float4 x = *(const float4*)(pA + o4 * 4);
    const float4 y = *(const float4*)(pB + o4 * 4);
    x.x += y.x; x.y += y.y; x.z += y.z; x.w += y.w;
    v4[o4] = x;
  }
  if (i == j) {
    const float* Di = ws + WS_D + (size_t)i * On;
#pragma unroll
    for (int o4 = 0; o4 < 16; o4++) {
      v4[o4].x += Di[o4 * 4 + 0];
      v4[o4].y += Di[o4 * 4 + 1];
      v4[o4].z += Di[o4 * 4 + 2];
      v4[o4].w += Di[o4 * 4 + 3];
    }
  }

  // ---- stage 1: v += W7^T * Tm[j,i] + W8^T * Tm[i,j] ----
  // c-outer runtime loop: live set = v4 (64) + 2 tile scalars.
  const float* W7t = ws + WS_W7T;
  const float* W8t = ws + WS_W8T;
  for (int c = 0; c < Cn; c++) {
    const int ix = sidx(c, braw);
    const float ac = Pji[ix];
    const float bc = Pij[ix];
    const float* w7 = W7t + c * On;   // wave-uniform -> scalar loads
    const float* w8 = W8t + c * On;
#pragma unroll
    for (int o4 = 0; o4 < 16; o4++) {
      v4[o4].x += w7[o4 * 4 + 0] * ac + w8[o4 * 4 + 0] * bc;
      v4[o4].y += w7[o4 * 4 + 1] * ac + w8[o4 * 4 + 1] * bc;
      v4[o4].z += w7[o4 * 4 + 2] * ac + w8[o4 * 4 + 2] * bc;
      v4[o4].w += w7[o4 * 4 + 3] * ac + w8[o4 * 4 + 3] * bc;
    }
  }

#pragma unroll
  for (int o4 = 0; o4 < 16; o4++) {
    v4[o4].x = fmaxf(v4[o4].x, 0.f);
    v4[o4].y = fmaxf(v4[o4].y, 0.f);
    v4[o4].z = fmaxf(v4[o4].z, 0.f);
    v4[o4].w = fmaxf(v4[o4].w, 0.f);
  }

  // ---- stage 2: out = W2 * h + b2 ----
  // p4-outer runtime loop: single float4 acc, store immediately.
  float* op = out + ((size_t)i * Ln + j) * On;
  for (int p4 = 0; p4 < 16; p4++) {
    float4 acc;
    acc.x = b2[p4 * 4 + 0];
    acc.y = b2[p4 * 4 + 1];
    acc.z = b2[p4 * 4 + 2];
    acc.w = b2[p4 * 4 + 3];
    const float* w0 = W2 + (size_t)(p4 * 4 + 0) * On;  // wave-uniform rows
    const float* w1 = W2 + (size_t)(p4 * 4 + 1) * On;
    const float* w2 = W2 + (size_t)(p4 * 4 + 2) * On;
    const float* w3 = W2 + (size_t)(p4 * 4 + 3) * On;
#pragma unroll
    for (int o4 = 0; o4 < 16; o4++) {
      const float4 h = v4[o4];
      acc.x += w0[o4*4+0] * h.x + w0[o4*4+1] * h.y + w0[o4*4+2] * h.z + w0[o4*4+3] * h.w;
      acc.y += w1[o4*4+0] * h.x + w1[o4*4+1] * h.y + w1[o4*4+2] * h.z + w1[o4*4+3] * h.w;
      acc.z += w2[o4*4+0] * h.x + w2[o4*4+1] * h.y + w2[o4*4+2] * h.z + w2[o4*4+3] * h.w;
      acc.w += w3[o4*4+0] * h.x + w3[o4*4+1] * h.y + w3[o4*4+2] * h.z + w3[o4*4+3] * h.w;
    }
    *(float4*)(op + p4 * 4) = acc;
  }
}

extern "C" void kernel_launch(void* const* d_in, const int* in_sizes, int n_in,
                              void* d_out, int out_size, void* d_ws, size_t ws_size,
                              hipStream_t stream) {
  (void)in_sizes; (void)n_in; (void)out_size; (void)ws_size;
  const float* T  = (const float*)d_in[0];
  const int*   Mk = (const int*)d_in[1];
  const float* W1 = (const float*)d_in[2];
  const float* b1 = (const float*)d_in[3];
  const float* W2 = (const float*)d_in[4];
  const float* b2 = (const float*)d_in[5];
  float* out = (float*)d_out;
  float* ws  = (float*)d_ws;

  k_colsum_diag<<<Ln, 256, 0, stream>>>(T, Mk, ws);
  {
    dim3 g(16, 16);
    k_rowsum_part<<<g, 256, 0, stream>>>(T, Mk, ws);
  }
  k_rowsum_reduce<<<64, 256, 0, stream>>>(ws);
  k_scalars<<<1, 256, 0, stream>>>(W1, b1, ws);
  k_node_terms<<<Ln, 64, 0, stream>>>(W1, ws);
  {
    const int nb = (Ln / 16) * (Ln / 16 + 1) / 2;  // 2080 triangular tile pairs
    k_main<<<nb, 512, 0, stream>>>(T, Mk, W2, b2, ws, out);
  }
}

// Round 3
// 656.583 us; speedup vs baseline: 3.6077x; 1.3755x over previous
//
#include <hip/hip_runtime.h>
#include <cstdint>

static constexpr int Ln = 1024;   // nodes
static constexpr int Cn = 16;     // in channels
static constexpr int On = 64;     // out channels
static constexpr int W1K = 15 * Cn; // 240

// ---- workspace layout (float offsets) ----
static constexpr size_t WS_COL  = 0;                        // [L][C]
static constexpr size_t WS_DIAG = WS_COL  + (size_t)Ln*Cn;  // [L][C]
static constexpr size_t WS_TR   = WS_DIAG + (size_t)Ln*Cn;  // [C]
static constexpr size_t WS_ALL  = WS_TR   + Cn;             // [C]
static constexpr size_t WS_C0   = WS_ALL  + Cn;             // [O]
static constexpr size_t WS_A    = WS_C0   + On;             // [L][O] col-node terms (c0 folded)
static constexpr size_t WS_B    = WS_A    + (size_t)Ln*On;  // [L][O] row-node terms
static constexpr size_t WS_D    = WS_B    + (size_t)Ln*On;  // [L][O] diagonal-only terms
static constexpr size_t WS_W7T  = WS_D    + (size_t)Ln*On;  // [C][O] W1 block 6 (transpose)
static constexpr size_t WS_W8T  = WS_W7T  + (size_t)Cn*On;  // [C][O] W1 block 7 (identity)
static constexpr size_t WS_W2T  = WS_W8T  + (size_t)Cn*On;  // [O][O] W2 transposed
static constexpr size_t WS_RPART= WS_W2T  + (size_t)On*On;  // [16][L][C] row_sum partials

__device__ __forceinline__ float4 masked4(const float* __restrict__ tp,
                                          const int* __restrict__ mp) {
  float4 t = *(const float4*)tp;
  int4  m = *(const int4*)mp;
  float4 r;
  r.x = m.x ? t.x : 0.f;
  r.y = m.y ? t.y : 0.f;
  r.z = m.z ? t.z : 0.f;
  r.w = m.w ? t.w : 0.f;
  return r;
}

// Tile LDS swizzle: element b (0..63) channel ch at b*16 + (ch ^ ((b>>1)&15)).
// Both b-major and transposed-b reads are conflict-free across a 64-lane wave.
__device__ __forceinline__ int tswz(int b, int ch) {
  return b * 16 + (ch ^ ((b >> 1) & 15));
}

// col_sum[i,c] = sum_j Tm[i,j,c]; also extracts diag. One block per row i. Coalesced.
__global__ __launch_bounds__(256) void k_colsum_diag(const float* __restrict__ T,
                                                     const int* __restrict__ Mk,
                                                     float* __restrict__ ws) {
  const int i = blockIdx.x;
  const int t = threadIdx.x;
  const float* rowT = T  + (size_t)i * Ln * Cn;
  const int*   rowM = Mk + (size_t)i * Ln * Cn;
  float s[Cn];
#pragma unroll
  for (int c = 0; c < Cn; c++) s[c] = 0.f;
  for (int j = t; j < Ln; j += 256) {
#pragma unroll
    for (int q = 0; q < 4; q++) {
      float4 v = masked4(rowT + j * Cn + q * 4, rowM + j * Cn + q * 4);
      s[q*4+0] += v.x; s[q*4+1] += v.y; s[q*4+2] += v.z; s[q*4+3] += v.w;
      if (j == i) {
        float* dg = ws + WS_DIAG + (size_t)i * Cn + q * 4;
        dg[0] = v.x; dg[1] = v.y; dg[2] = v.z; dg[3] = v.w;
      }
    }
  }
  __shared__ float red[256][Cn + 1];
#pragma unroll
  for (int c = 0; c < Cn; c++) red[t][c] = s[c];
  __syncthreads();
  for (int off = 128; off > 0; off >>= 1) {
    if (t < off) {
#pragma unroll
      for (int c = 0; c < Cn; c++) red[t][c] += red[t + off][c];
    }
    __syncthreads();
  }
  if (t < Cn) ws[WS_COL + (size_t)i * Cn + t] = red[0][t];
}

// Coalesced row_sum partials: block (bj, bi) handles 64 cols x 64-row band.
__global__ __launch_bounds__(256) void k_rowsum_part(const float* __restrict__ T,
                                                     const int* __restrict__ Mk,
                                                     float* __restrict__ ws) {
  const int bj = blockIdx.x, bi = blockIdx.y, t = threadIdx.x;
  const int jl = t >> 2, c4 = t & 3;
  const int j = bj * 64 + jl;
  float4 acc = {0.f, 0.f, 0.f, 0.f};
  for (int ii = 0; ii < 64; ii++) {
    const int i = bi * 64 + ii;
    const size_t base = ((size_t)i * Ln + j) * Cn + c4 * 4;
    float4 v = masked4(T + base, Mk + base);
    acc.x += v.x; acc.y += v.y; acc.z += v.z; acc.w += v.w;
  }
  *(float4*)(ws + WS_RPART + ((size_t)bi * Ln + j) * Cn + c4 * 4) = acc;
}

// trace, all_sum, c0, transposed W7/W8 blocks, transposed W2. Single block.
__global__ __launch_bounds__(256) void k_scalars(const float* __restrict__ W1,
                                                 const float* __restrict__ b1,
                                                 const float* __restrict__ W2,
                                                 float* __restrict__ ws) {
  const int t = threadIdx.x;
  __shared__ float redt[16][17], reda[16][17];
  __shared__ float trs[Cn], als[Cn];

  for (int idx = t; idx < 2 * Cn * On; idx += 256) {
    int which = idx >> 10;      // Cn*On == 1024
    int rem = idx & 1023;
    int c = rem >> 6, o = rem & 63;
    ws[(which ? WS_W8T : WS_W7T) + rem] = W1[o * W1K + (which ? 7 : 6) * Cn + c];
  }
  for (int idx = t; idx < On * On; idx += 256) {
    int o = idx >> 6, p = idx & 63;
    ws[WS_W2T + idx] = W2[p * On + o];     // W2T[o][p]
  }
  {
    int c = t & 15, seg = t >> 4;
    float a = 0.f, b = 0.f;
    for (int i = seg * 64; i < seg * 64 + 64; i++) {
      a += ws[WS_DIAG + (size_t)i * Cn + c];
      b += ws[WS_COL  + (size_t)i * Cn + c];
    }
    redt[seg][c] = a;
    reda[seg][c] = b;
  }
  __syncthreads();
  if (t < Cn) {
    float ta = 0.f, tb = 0.f;
    for (int s = 0; s < 16; s++) { ta += redt[s][t]; tb += reda[s][t]; }
    ws[WS_TR + t] = ta; ws[WS_ALL + t] = tb;
    trs[t] = ta; als[t] = tb;
  }
  __syncthreads();
  if (t < On) {
    float acc = b1[t];
#pragma unroll
    for (int c = 0; c < Cn; c++)
      acc += W1[t * W1K + 8 * Cn + c] * trs[c] + W1[t * W1K + 14 * Cn + c] * als[c];
    ws[WS_C0 + t] = acc;
  }
}

// Per-node A/B/D vectors; row_sum reduce folded in. 4 nodes per 256-thread block.
__global__ __launch_bounds__(256) void k_node_terms(const float* __restrict__ W1,
                                                    float* __restrict__ ws) {
  const int t = threadIdx.x;
  const int g = t >> 6, o = t & 63;
  const int n = blockIdx.x * 4 + g;
  __shared__ float sd[4][Cn], sr[4][Cn], sc[4][Cn];
  __shared__ float st[Cn], sa[Cn];
  if (t < Cn) { st[t] = ws[WS_TR + t]; sa[t] = ws[WS_ALL + t]; }
  if (o < Cn) {
    sd[g][o] = ws[WS_DIAG + (size_t)n * Cn + o];
    sc[g][o] = ws[WS_COL  + (size_t)n * Cn + o];
    float s = 0.f;
#pragma unroll
    for (int p = 0; p < 16; p++)
      s += ws[WS_RPART + ((size_t)p * Ln + n) * Cn + o];
    sr[g][o] = s;
  }
  __syncthreads();
  const float* w = W1 + o * W1K;
  float a = 0.f, b = 0.f, d = 0.f;
#pragma unroll
  for (int c = 0; c < Cn; c++) {
    a += w[ 1*Cn + c] * sd[g][c] + w[ 9*Cn + c] * sr[g][c] + w[10*Cn + c] * sc[g][c];
    b += w[ 2*Cn + c] * sd[g][c] + w[12*Cn + c] * sc[g][c] + w[13*Cn + c] * sr[g][c];
    d += w[ 0*Cn + c] * sd[g][c] + w[ 3*Cn + c] * sr[g][c] + w[ 4*Cn + c] * sc[g][c]
       + w[ 5*Cn + c] * st[c] + w[11*Cn + c] * sa[c];
  }
  ws[WS_A + (size_t)n * On + o] = a + ws[WS_C0 + o];   // fold c0
  ws[WS_B + (size_t)n * On + o] = b;
  ws[WS_D + (size_t)n * On + o] = d;
}

// Main fused kernel. 8x8-node triangular pair tiles (8256 blocks), 256 threads.
// Thread = (pair slot s in [0,128), channel half hf). Per-thread accumulator is
// 32 floats MAX in each phase (the 64-float version spilled in rounds 0-2).
// Phase 1: h-half -> relu -> LDS hbuf[128][65]. Phase 2: 64x32 GEMV from LDS h
// with wave-uniform (s_load) weights from pre-transposed W2T.
__global__ __launch_bounds__(256, 2) void k_main(const float* __restrict__ T,
                                                 const int* __restrict__ Mk,
                                                 const float* __restrict__ b2,
                                                 const float* __restrict__ ws,
                                                 float* __restrict__ out) {
  // ---- triangular decode over 128 tiles: base(I) = I*(257-I)/2 ----
  const int kb = blockIdx.x;
  int I = (int)((257.0f - sqrtf(66049.0f - 8.0f * (float)kb)) * 0.5f);
  while ((I + 1) * (257 - (I + 1)) / 2 <= kb) ++I;
  while (I * (257 - I) / 2 > kb) --I;
  const int J = I + (kb - I * (257 - I) / 2);

  const int t = threadIdx.x;

  __shared__ float sA[64 * 16];       // swizzled; b=r*8+c -> Tm[I*8+r, J*8+c, ch]
  __shared__ float sB[64 * 16];       // b=r*8+c -> Tm[J*8+r, I*8+c, ch]
  __shared__ float nAJ[8 * 68], nBI[8 * 68], nAI[8 * 68], nBJ[8 * 68];
  __shared__ float hbuf[128 * 65];    // h[slot][o], stride 65 -> conflict-free

  // ---- stage tiles: one float4 of T+Mk per thread per tile ----
  {
    const int row = t >> 5, rem = t & 31, colq = rem >> 2, c4 = rem & 3;
    const int b = row * 8 + colq;
    const int f = (b >> 1) & 15;
    {
      const size_t g = (((size_t)(I * 8 + row)) * Ln + (J * 8 + colq)) * Cn + c4 * 4;
      float4 v = masked4(T + g, Mk + g);
      sA[b * 16 + ((c4 * 4 + 0) ^ f)] = v.x;
      sA[b * 16 + ((c4 * 4 + 1) ^ f)] = v.y;
      sA[b * 16 + ((c4 * 4 + 2) ^ f)] = v.z;
      sA[b * 16 + ((c4 * 4 + 3) ^ f)] = v.w;
    }
    {
      const size_t g = (((size_t)(J * 8 + row)) * Ln + (I * 8 + colq)) * Cn + c4 * 4;
      float4 v = masked4(T + g, Mk + g);
      sB[b * 16 + ((c4 * 4 + 0) ^ f)] = v.x;
      sB[b * 16 + ((c4 * 4 + 1) ^ f)] = v.y;
      sB[b * 16 + ((c4 * 4 + 2) ^ f)] = v.z;
      sB[b * 16 + ((c4 * 4 + 3) ^ f)] = v.w;
    }
  }
  // ---- stage node vectors: 512 float4s, 2 per thread ----
#pragma unroll
  for (int k = 0; k < 2; k++) {
    const int fidx = t + k * 256;                 // 0..511
    const int arr = fidx >> 7, rem = fidx & 127, node = rem >> 4, o4 = rem & 15;
    size_t src;
    float* dst;
    switch (arr) {
      case 0: src = WS_A + ((size_t)(J * 8 + node)) * On; dst = nAJ; break;
      case 1: src = WS_B + ((size_t)(I * 8 + node)) * On; dst = nBI; break;
      case 2: src = WS_A + ((size_t)(I * 8 + node)) * On; dst = nAI; break;
      default: src = WS_B + ((size_t)(J * 8 + node)) * On; dst = nBJ; break;
    }
    float4 v = *(const float4*)(ws + src + o4 * 4);
    *(float4*)(dst + node * 68 + o4 * 4) = v;
  }
  __syncthreads();

  const int hfu = __builtin_amdgcn_readfirstlane((t >> 7) & 1);  // wave-uniform
  const int s = t & 127;
  const int ori = s >> 6;                 // 0: out[I-tile,J-tile]; 1: out[J,I]
  const int rr = (s >> 3) & 7, cc = s & 7;
  const int u = (ori ? J : I) * 8 + rr;   // output row node
  const int v = (ori ? I : J) * 8 + cc;   // output col node
  const float* Puv = ori ? sB : sA;       // Tm[u,v,:] lives here at b=rr*8+cc
  const float* Pvu = ori ? sA : sB;       // Tm[v,u,:] at b=cc*8+rr
  const int buv = rr * 8 + cc, bvu = cc * 8 + rr;
  const int fuv = (buv >> 1) & 15, fvu = (bvu >> 1) & 15;
  const float* pAv = (ori ? nAI : nAJ) + cc * 68 + hfu * 32;
  const float* pBu = (ori ? nBJ : nBI) + rr * 68 + hfu * 32;

  // ---- phase 1: h-half = A[v]+B[u](+D)+W7^T Tm[v,u]+W8^T Tm[u,v] ----
  float vac[32];
#pragma unroll
  for (int o4 = 0; o4 < 8; o4++) {
    const float4 xa = *(const float4*)(pAv + o4 * 4);
    const float4 xb = *(const float4*)(pBu + o4 * 4);
    vac[o4*4+0] = xa.x + xb.x;
    vac[o4*4+1] = xa.y + xb.y;
    vac[o4*4+2] = xa.z + xb.z;
    vac[o4*4+3] = xa.w + xb.w;
  }
  if (u == v) {
    const float* Du = ws + WS_D + (size_t)u * On + hfu * 32;
#pragma unroll
    for (int o4 = 0; o4 < 8; o4++) {
      const float4 dv = *(const float4*)(Du + o4 * 4);
      vac[o4*4+0] += dv.x;
      vac[o4*4+1] += dv.y;
      vac[o4*4+2] += dv.z;
      vac[o4*4+3] += dv.w;
    }
  }

  const float* W7 = ws + WS_W7T + hfu * 32;   // [c][64] rows; uniform -> s_load
  const float* W8 = ws + WS_W8T + hfu * 32;
  for (int c = 0; c < Cn; c++) {
    const float avu = Pvu[bvu * 16 + (c ^ fvu)];
    const float auv = Puv[buv * 16 + (c ^ fuv)];
    const float* w7 = W7 + c * On;
    const float* w8 = W8 + c * On;
#pragma unroll
    for (int oo = 0; oo < 32; oo++)
      vac[oo] += w7[oo] * avu + w8[oo] * auv;
  }

  {
    float* hw = hbuf + s * 65 + hfu * 32;
#pragma unroll
    for (int oo = 0; oo < 32; oo++)
      hw[oo] = fmaxf(vac[oo], 0.f);
  }
  __syncthreads();

  // ---- phase 2: out-half = W2T^T h + b2-half ----
  float acc[32];
#pragma unroll
  for (int p4 = 0; p4 < 8; p4++) {
    const float4 bv = *(const float4*)(b2 + hfu * 32 + p4 * 4);
    acc[p4*4+0] = bv.x;
    acc[p4*4+1] = bv.y;
    acc[p4*4+2] = bv.z;
    acc[p4*4+3] = bv.w;
  }
  const float* hrow = hbuf + s * 65;
  const float* W2c = ws + WS_W2T + hfu * 32;  // W2T[o][p], uniform rows
  for (int o4 = 0; o4 < 16; o4++) {
    const float h0 = hrow[o4 * 4 + 0];
    const float h1 = hrow[o4 * 4 + 1];
    const float h2 = hrow[o4 * 4 + 2];
    const float h3 = hrow[o4 * 4 + 3];
    const float* w0 = W2c + (size_t)(o4 * 4 + 0) * On;
    const float* w1 = W2c + (size_t)(o4 * 4 + 1) * On;
    const float* w2 = W2c + (size_t)(o4 * 4 + 2) * On;
    const float* w3 = W2c + (size_t)(o4 * 4 + 3) * On;
#pragma unroll
    for (int pp = 0; pp < 32; pp++)
      acc[pp] += w0[pp] * h0 + w1[pp] * h1 + w2[pp] * h2 + w3[pp] * h3;
  }

  float* op = out + ((size_t)u * Ln + v) * On + hfu * 32;
#pragma unroll
  for (int p4 = 0; p4 < 8; p4++) {
    float4 o4v;
    o4v.x = acc[p4*4+0];
    o4v.y = acc[p4*4+1];
    o4v.z = acc[p4*4+2];
    o4v.w = acc[p4*4+3];
    *(float4*)(op + p4 * 4) = o4v;
  }
}

extern "C" void kernel_launch(void* const* d_in, const int* in_sizes, int n_in,
                              void* d_out, int out_size, void* d_ws, size_t ws_size,
                              hipStream_t stream) {
  (void)in_sizes; (void)n_in; (void)out_size; (void)ws_size;
  const float* T  = (const float*)d_in[0];
  const int*   Mk = (const int*)d_in[1];
  const float* W1 = (const float*)d_in[2];
  const float* b1 = (const float*)d_in[3];
  const float* W2 = (const float*)d_in[4];
  const float* b2 = (const float*)d_in[5];
  float* out = (float*)d_out;
  float* ws  = (float*)d_ws;

  k_colsum_diag<<<Ln, 256, 0, stream>>>(T, Mk, ws);
  {
    dim3 g(16, 16);
    k_rowsum_part<<<g, 256, 0, stream>>>(T, Mk, ws);
  }
  k_scalars<<<1, 256, 0, stream>>>(W1, b1, W2, ws);
  k_node_terms<<<Ln / 4, 256, 0, stream>>>(W1, ws);
  {
    const int nb = 128 * 129 / 2;   // 8256 triangular 8x8 tile pairs
    k_main<<<nb, 256, 0, stream>>>(T, Mk, b2, ws, out);
  }
}

// Round 4
// 488.638 us; speedup vs baseline: 4.8476x; 1.3437x over previous
//
#include <hip/hip_runtime.h>
#include <cstdint>

static constexpr int Ln = 1024;   // nodes
static constexpr int Cn = 16;     // in channels
static constexpr int On = 64;     // out channels
static constexpr int W1K = 15 * Cn; // 240

// ---- workspace layout (float offsets) ----
static constexpr size_t WS_COL  = 0;                        // [L][C]
static constexpr size_t WS_DIAG = WS_COL  + (size_t)Ln*Cn;  // [L][C]
static constexpr size_t WS_TR   = WS_DIAG + (size_t)Ln*Cn;  // [C]
static constexpr size_t WS_ALL  = WS_TR   + Cn;             // [C]
static constexpr size_t WS_C0   = WS_ALL  + Cn;             // [O]
static constexpr size_t WS_A    = WS_C0   + On;             // [L][O] col-node terms (c0 folded)
static constexpr size_t WS_B    = WS_A    + (size_t)Ln*On;  // [L][O] row-node terms
static constexpr size_t WS_D    = WS_B    + (size_t)Ln*On;  // [L][O] diagonal-only terms
static constexpr size_t WS_W7T  = WS_D    + (size_t)Ln*On;  // [C][O] W1 block 6 (transpose)
static constexpr size_t WS_W8T  = WS_W7T  + (size_t)Cn*On;  // [C][O] W1 block 7 (identity)
static constexpr size_t WS_W2B  = WS_W8T  + (size_t)Cn*On;  // [O][O] W2 as bf16 (u16), row-major
static constexpr size_t WS_RPART= WS_W2B  + 1024;           // [16][L][C] row_sum partials

typedef __attribute__((ext_vector_type(8))) short short8;
typedef __attribute__((ext_vector_type(4))) float f32x4;
typedef __attribute__((ext_vector_type(4))) unsigned int u32x4;

__device__ __forceinline__ float4 masked4(const float* __restrict__ tp,
                                          const int* __restrict__ mp) {
  float4 t = *(const float4*)tp;
  int4  m = *(const int4*)mp;
  float4 r;
  r.x = m.x ? t.x : 0.f;
  r.y = m.y ? t.y : 0.f;
  r.z = m.z ? t.z : 0.f;
  r.w = m.w ? t.w : 0.f;
  return r;
}

__device__ __forceinline__ uint16_t f2bf(float x) {   // RNE fp32 -> bf16
  uint32_t u = __float_as_uint(x);
  uint32_t r = u + 0x7FFFu + ((u >> 16) & 1u);
  return (uint16_t)(r >> 16);
}

// col_sum[i,c] = sum_j Tm[i,j,c]; also extracts diag. One block per row i. Coalesced.
__global__ __launch_bounds__(256) void k_colsum_diag(const float* __restrict__ T,
                                                     const int* __restrict__ Mk,
                                                     float* __restrict__ ws) {
  const int i = blockIdx.x;
  const int t = threadIdx.x;
  const float* rowT = T  + (size_t)i * Ln * Cn;
  const int*   rowM = Mk + (size_t)i * Ln * Cn;
  float s[Cn];
#pragma unroll
  for (int c = 0; c < Cn; c++) s[c] = 0.f;
  for (int j = t; j < Ln; j += 256) {
#pragma unroll
    for (int q = 0; q < 4; q++) {
      float4 v = masked4(rowT + j * Cn + q * 4, rowM + j * Cn + q * 4);
      s[q*4+0] += v.x; s[q*4+1] += v.y; s[q*4+2] += v.z; s[q*4+3] += v.w;
      if (j == i) {
        float* dg = ws + WS_DIAG + (size_t)i * Cn + q * 4;
        dg[0] = v.x; dg[1] = v.y; dg[2] = v.z; dg[3] = v.w;
      }
    }
  }
  __shared__ float red[256][Cn + 1];
#pragma unroll
  for (int c = 0; c < Cn; c++) red[t][c] = s[c];
  __syncthreads();
  for (int off = 128; off > 0; off >>= 1) {
    if (t < off) {
#pragma unroll
      for (int c = 0; c < Cn; c++) red[t][c] += red[t + off][c];
    }
    __syncthreads();
  }
  if (t < Cn) ws[WS_COL + (size_t)i * Cn + t] = red[0][t];
}

// Coalesced row_sum partials: block (bj, bi) handles 64 cols x 64-row band.
__global__ __launch_bounds__(256) void k_rowsum_part(const float* __restrict__ T,
                                                     const int* __restrict__ Mk,
                                                     float* __restrict__ ws) {
  const int bj = blockIdx.x, bi = blockIdx.y, t = threadIdx.x;
  const int jl = t >> 2, c4 = t & 3;
  const int j = bj * 64 + jl;
  float4 acc = {0.f, 0.f, 0.f, 0.f};
  for (int ii = 0; ii < 64; ii++) {
    const int i = bi * 64 + ii;
    const size_t base = ((size_t)i * Ln + j) * Cn + c4 * 4;
    float4 v = masked4(T + base, Mk + base);
    acc.x += v.x; acc.y += v.y; acc.z += v.z; acc.w += v.w;
  }
  *(float4*)(ws + WS_RPART + ((size_t)bi * Ln + j) * Cn + c4 * 4) = acc;
}

// trace, all_sum, c0, transposed W7/W8 blocks, bf16 W2. Single block.
__global__ __launch_bounds__(256) void k_scalars(const float* __restrict__ W1,
                                                 const float* __restrict__ b1,
                                                 const float* __restrict__ W2,
                                                 float* __restrict__ ws) {
  const int t = threadIdx.x;
  __shared__ float redt[16][17], reda[16][17];
  __shared__ float trs[Cn], als[Cn];

  for (int idx = t; idx < 2 * Cn * On; idx += 256) {
    int which = idx >> 10;      // Cn*On == 1024
    int rem = idx & 1023;
    int c = rem >> 6, o = rem & 63;
    ws[(which ? WS_W8T : WS_W7T) + rem] = W1[o * W1K + (which ? 7 : 6) * Cn + c];
  }
  {
    uint16_t* w2b = (uint16_t*)(ws + WS_W2B);
    for (int idx = t; idx < On * On; idx += 256)
      w2b[idx] = f2bf(W2[idx]);            // row-major [n][k]
  }
  {
    int c = t & 15, seg = t >> 4;
    float a = 0.f, b = 0.f;
    for (int i = seg * 64; i < seg * 64 + 64; i++) {
      a += ws[WS_DIAG + (size_t)i * Cn + c];
      b += ws[WS_COL  + (size_t)i * Cn + c];
    }
    redt[seg][c] = a;
    reda[seg][c] = b;
  }
  __syncthreads();
  if (t < Cn) {
    float ta = 0.f, tb = 0.f;
    for (int s = 0; s < 16; s++) { ta += redt[s][t]; tb += reda[s][t]; }
    ws[WS_TR + t] = ta; ws[WS_ALL + t] = tb;
    trs[t] = ta; als[t] = tb;
  }
  __syncthreads();
  if (t < On) {
    float acc = b1[t];
#pragma unroll
    for (int c = 0; c < Cn; c++)
      acc += W1[t * W1K + 8 * Cn + c] * trs[c] + W1[t * W1K + 14 * Cn + c] * als[c];
    ws[WS_C0 + t] = acc;
  }
}

// Per-node A/B/D vectors; row_sum reduce folded in. 4 nodes per 256-thread block.
__global__ __launch_bounds__(256) void k_node_terms(const float* __restrict__ W1,
                                                    float* __restrict__ ws) {
  const int t = threadIdx.x;
  const int g = t >> 6, o = t & 63;
  const int n = blockIdx.x * 4 + g;
  __shared__ float sd[4][Cn], sr[4][Cn], sc[4][Cn];
  __shared__ float st[Cn], sa[Cn];
  if (t < Cn) { st[t] = ws[WS_TR + t]; sa[t] = ws[WS_ALL + t]; }
  if (o < Cn) {
    sd[g][o] = ws[WS_DIAG + (size_t)n * Cn + o];
    sc[g][o] = ws[WS_COL  + (size_t)n * Cn + o];
    float s = 0.f;
#pragma unroll
    for (int p = 0; p < 16; p++)
      s += ws[WS_RPART + ((size_t)p * Ln + n) * Cn + o];
    sr[g][o] = s;
  }
  __syncthreads();
  const float* w = W1 + o * W1K;
  float a = 0.f, b = 0.f, d = 0.f;
#pragma unroll
  for (int c = 0; c < Cn; c++) {
    a += w[ 1*Cn + c] * sd[g][c] + w[ 9*Cn + c] * sr[g][c] + w[10*Cn + c] * sc[g][c];
    b += w[ 2*Cn + c] * sd[g][c] + w[12*Cn + c] * sc[g][c] + w[13*Cn + c] * sr[g][c];
    d += w[ 0*Cn + c] * sd[g][c] + w[ 3*Cn + c] * sr[g][c] + w[ 4*Cn + c] * sc[g][c]
       + w[ 5*Cn + c] * st[c] + w[11*Cn + c] * sa[c];
  }
  ws[WS_A + (size_t)n * On + o] = a + ws[WS_C0 + o];   // fold c0
  ws[WS_B + (size_t)n * On + o] = b;
  ws[WS_D + (size_t)n * On + o] = d;
}

// Main fused kernel. 8x8-node triangular pair tiles (8256 blocks), 256 threads.
// Phase 1 (VALU, fp32): h-half per thread (32-reg acc, proven spill-free R3),
//   relu -> bf16 -> LDS hb[128][72 bf16] (UNION with phase-1 tiles/nodes: LDS
//   drops 50 KB -> 18.4 KB, occupancy cap 37.5% -> waves-limited ~87%).
// Phase 2 (MFMA): out[128x64] = hb[128x64] x W2^T via mfma_f32_16x16x32_bf16;
//   wave w owns out-channel tile n0=w*16, B-frags from global bf16 W2 (L2-hot).
__global__ __launch_bounds__(256, 2) void k_main(const float* __restrict__ T,
                                                 const int* __restrict__ Mk,
                                                 const float* __restrict__ b2,
                                                 const float* __restrict__ ws,
                                                 float* __restrict__ out) {
  // ---- triangular decode over 128 tiles: base(I) = I*(257-I)/2 ----
  const int kb = blockIdx.x;
  int I = (int)((257.0f - sqrtf(66049.0f - 8.0f * (float)kb)) * 0.5f);
  while ((I + 1) * (257 - (I + 1)) / 2 <= kb) ++I;
  while (I * (257 - I) / 2 > kb) --I;
  const int J = I + (kb - I * (257 - I) / 2);

  const int t = threadIdx.x;

  // Union: phase 1 uses [sA 1024 | sB 1024 | 4x node arrays 544] = 4224 floats;
  // phase 2 reuses the same memory as hb (128 rows x 36 dwords bf16 h) = 4608.
  __shared__ float smem[4608];                 // 18432 B
  float* sA = smem;                            // swizzled tile, b=r*8+c
  float* sB = smem + 1024;
  float* nAJ = smem + 2048;
  float* nBI = smem + 2048 + 544;
  float* nAI = smem + 2048 + 1088;
  float* nBJ = smem + 2048 + 1632;
  uint32_t* hb32 = (uint32_t*)smem;            // phase 2 view

  // ---- stage tiles (mask applied) ----
  {
    const int row = t >> 5, rem = t & 31, colq = rem >> 2, c4 = rem & 3;
    const int b = row * 8 + colq;
    const int f = (b >> 1) & 15;
    {
      const size_t g = (((size_t)(I * 8 + row)) * Ln + (J * 8 + colq)) * Cn + c4 * 4;
      float4 v = masked4(T + g, Mk + g);
      sA[b * 16 + ((c4 * 4 + 0) ^ f)] = v.x;
      sA[b * 16 + ((c4 * 4 + 1) ^ f)] = v.y;
      sA[b * 16 + ((c4 * 4 + 2) ^ f)] = v.z;
      sA[b * 16 + ((c4 * 4 + 3) ^ f)] = v.w;
    }
    {
      const size_t g = (((size_t)(J * 8 + row)) * Ln + (I * 8 + colq)) * Cn + c4 * 4;
      float4 v = masked4(T + g, Mk + g);
      sB[b * 16 + ((c4 * 4 + 0) ^ f)] = v.x;
      sB[b * 16 + ((c4 * 4 + 1) ^ f)] = v.y;
      sB[b * 16 + ((c4 * 4 + 2) ^ f)] = v.z;
      sB[b * 16 + ((c4 * 4 + 3) ^ f)] = v.w;
    }
  }
  // ---- stage node vectors: 512 float4s, 2 per thread ----
#pragma unroll
  for (int k = 0; k < 2; k++) {
    const int fidx = t + k * 256;                 // 0..511
    const int arr = fidx >> 7, rem = fidx & 127, node = rem >> 4, o4 = rem & 15;
    size_t src;
    float* dst;
    switch (arr) {
      case 0: src = WS_A + ((size_t)(J * 8 + node)) * On; dst = nAJ; break;
      case 1: src = WS_B + ((size_t)(I * 8 + node)) * On; dst = nBI; break;
      case 2: src = WS_A + ((size_t)(I * 8 + node)) * On; dst = nAI; break;
      default: src = WS_B + ((size_t)(J * 8 + node)) * On; dst = nBJ; break;
    }
    float4 v = *(const float4*)(ws + src + o4 * 4);
    *(float4*)(dst + node * 68 + o4 * 4) = v;
  }
  __syncthreads();

  const int hfu = __builtin_amdgcn_readfirstlane((t >> 7) & 1);  // wave-uniform
  const int s = t & 127;
  const int ori = s >> 6;                 // 0: out[I-tile,J-tile]; 1: out[J,I]
  const int rr = (s >> 3) & 7, cc = s & 7;
  const int u = (ori ? J : I) * 8 + rr;   // output row node
  const int v = (ori ? I : J) * 8 + cc;   // output col node
  const float* Puv = ori ? sB : sA;       // Tm[u,v,:] at b=rr*8+cc
  const float* Pvu = ori ? sA : sB;       // Tm[v,u,:] at b=cc*8+rr
  const int buv = rr * 8 + cc, bvu = cc * 8 + rr;
  const int fuv = (buv >> 1) & 15, fvu = (bvu >> 1) & 15;
  const float* pAv = (ori ? nAI : nAJ) + cc * 68 + hfu * 32;
  const float* pBu = (ori ? nBJ : nBI) + rr * 68 + hfu * 32;

  // ---- phase 1: h-half = A[v]+B[u](+D)+W7^T Tm[v,u]+W8^T Tm[u,v] ----
  float vac[32];
#pragma unroll
  for (int o4 = 0; o4 < 8; o4++) {
    const float4 xa = *(const float4*)(pAv + o4 * 4);
    const float4 xb = *(const float4*)(pBu + o4 * 4);
    vac[o4*4+0] = xa.x + xb.x;
    vac[o4*4+1] = xa.y + xb.y;
    vac[o4*4+2] = xa.z + xb.z;
    vac[o4*4+3] = xa.w + xb.w;
  }
  if (u == v) {
    const float* Du = ws + WS_D + (size_t)u * On + hfu * 32;
#pragma unroll
    for (int o4 = 0; o4 < 8; o4++) {
      const float4 dv = *(const float4*)(Du + o4 * 4);
      vac[o4*4+0] += dv.x;
      vac[o4*4+1] += dv.y;
      vac[o4*4+2] += dv.z;
      vac[o4*4+3] += dv.w;
    }
  }

  const float* W7 = ws + WS_W7T + hfu * 32;   // uniform rows -> s_load
  const float* W8 = ws + WS_W8T + hfu * 32;
  for (int c = 0; c < Cn; c++) {
    const float avu = Pvu[bvu * 16 + (c ^ fvu)];
    const float auv = Puv[buv * 16 + (c ^ fuv)];
    const float* w7 = W7 + c * On;
    const float* w8 = W8 + c * On;
#pragma unroll
    for (int oo = 0; oo < 32; oo++)
      vac[oo] += w7[oo] * avu + w8[oo] * auv;
  }

  // ---- all phase-1 LDS reads done; overwrite union with bf16 h ----
  __syncthreads();
  {
    uint32_t* hrow = hb32 + s * 36 + hfu * 16;
#pragma unroll
    for (int q = 0; q < 16; q++) {
      const uint32_t lo = f2bf(fmaxf(vac[2*q+0], 0.f));
      const uint32_t hi = f2bf(fmaxf(vac[2*q+1], 0.f));
      hrow[q] = lo | (hi << 16);
    }
  }
  __syncthreads();

  // ---- phase 2: out = hb x W2^T via MFMA; wave w -> out-channels [w*16, +16) ----
  const int wv = t >> 6, l = t & 63;
  const int n0 = wv * 16;
  const int lc = l & 15, lk = l >> 4;
  const char* wb = (const char*)(ws + WS_W2B);
  const u32x4 rb0 = *(const u32x4*)(wb + (size_t)(n0 + lc) * 128 + lk * 16);
  const u32x4 rb1 = *(const u32x4*)(wb + (size_t)(n0 + lc) * 128 + 64 + lk * 16);
  const short8 bf0 = __builtin_bit_cast(short8, rb0);
  const short8 bf1 = __builtin_bit_cast(short8, rb1);
  const float bias = b2[n0 + lc];

#pragma unroll
  for (int mt = 0; mt < 8; mt++) {
    const int m0 = mt * 16;
    const u32x4 ra0 = *(const u32x4*)(hb32 + (m0 + lc) * 36 + lk * 4);
    const u32x4 ra1 = *(const u32x4*)(hb32 + (m0 + lc) * 36 + 16 + lk * 4);
    f32x4 c = {0.f, 0.f, 0.f, 0.f};
    c = __builtin_amdgcn_mfma_f32_16x16x32_bf16(__builtin_bit_cast(short8, ra0), bf0, c, 0, 0, 0);
    c = __builtin_amdgcn_mfma_f32_16x16x32_bf16(__builtin_bit_cast(short8, ra1), bf1, c, 0, 0, 0);
#pragma unroll
    for (int r = 0; r < 4; r++) {
      const int slot = m0 + lk * 4 + r;          // C row -> h slot
      const int so = slot >> 6, sr_ = (slot >> 3) & 7, sc_ = slot & 7;
      const int uu = (so ? J : I) * 8 + sr_;
      const int vv = (so ? I : J) * 8 + sc_;
      out[((size_t)uu * Ln + vv) * On + n0 + lc] = c[r] + bias;
    }
  }
}

extern "C" void kernel_launch(void* const* d_in, const int* in_sizes, int n_in,
                              void* d_out, int out_size, void* d_ws, size_t ws_size,
                              hipStream_t stream) {
  (void)in_sizes; (void)n_in; (void)out_size; (void)ws_size;
  const float* T  = (const float*)d_in[0];
  const int*   Mk = (const int*)d_in[1];
  const float* W1 = (const float*)d_in[2];
  const float* b1 = (const float*)d_in[3];
  const float* W2 = (const float*)d_in[4];
  const float* b2 = (const float*)d_in[5];
  float* out = (float*)d_out;
  float* ws  = (float*)d_ws;

  k_colsum_diag<<<Ln, 256, 0, stream>>>(T, Mk, ws);
  {
    dim3 g(16, 16);
    k_rowsum_part<<<g, 256, 0, stream>>>(T, Mk, ws);
  }
  k_scalars<<<1, 256, 0, stream>>>(W1, b1, W2, ws);
  k_node_terms<<<Ln / 4, 256, 0, stream>>>(W1, ws);
  {
    const int nb = 128 * 129 / 2;   // 8256 triangular 8x8 tile pairs
    k_main<<<nb, 256, 0, stream>>>(T, Mk, b2, ws, out);
  }
}